// Round 2
// baseline (58128.552 us; speedup 1.0000x reference)
//
#include <hip/hip_runtime.h>

typedef unsigned short u16;
typedef unsigned int   u32;

#define Bb   32
#define Tt   256
#define Ss   512
#define Hh   512
#define G4H  2048

// ---- dtype-polymorphic load/store: F32 ? fp32 : bf16 ------------------------
template<bool F32>
__device__ __forceinline__ float ldin(const void* p, size_t i) {
    if constexpr (F32) {
        return ((const float*)p)[i];
    } else {
        u32 v = ((u32)((const u16*)p)[i]) << 16;
        return __uint_as_float(v);
    }
}
template<bool F32>
__device__ __forceinline__ void stout(void* p, size_t i, float f) {
    if constexpr (F32) {
        ((float*)p)[i] = f;
    } else {
        u32 x = __float_as_uint(f);
        u32 r = x + 0x7fffu + ((x >> 16) & 1u);   // RNE
        ((u16*)p)[i] = (u16)(r >> 16);
    }
}

// ---------------------------------------------------------------------------
// K0: dtype detector. True bf16 N(0,1)-scale data never has exponent >= 0xC8
// (|x| >= 2^73). fp32 viewed as u16s: low-mantissa halves ~uniform -> ~22%
// have exponent >= 0xC8. Count over 16384 u16s of ctx.
// ---------------------------------------------------------------------------
__global__ __launch_bounds__(256) void k_detect(const void* ctx, int* flag) {
    __shared__ int cnt;
    if (threadIdx.x == 0) cnt = 0;
    __syncthreads();
    const u16* p = (const u16*)ctx;
    int c = 0;
    for (int i = threadIdx.x; i < 16384; i += 256) {
        int e = (p[i] >> 7) & 0xFF;
        if (e >= 0xC8) c++;
    }
    atomicAdd(&cnt, c);
    __syncthreads();
    if (threadIdx.x == 0) *flag = (cnt > 64) ? 1 : 0;
}

// ---------------------------------------------------------------------------
// K1: gates = [x_t, h] @ [Wi; Wh] + bi + bh, LSTM pointwise -> hy, cy
// grid: 512 = 32 b x 16 jc (32 gate-cols each), 256 threads
// wOff/bOff: layer element offsets into Wi/Wh/bi/bh
// ---------------------------------------------------------------------------
template<bool F32>
__device__ __forceinline__ void gates_body(
    const void* xsrc, const void* h0, const void* c0,
    const void* Wi, const void* bi, const void* Wh, const void* bh,
    size_t wOff, size_t bOff,
    const float* h_ws, float* c_ws, float* hy_ws,
    void* out, unsigned long long offC1, int t, int writeC1)
{
    __shared__ float xh[1024];
    __shared__ float red[4][32][8];
    __shared__ float ga[4][32];

    const int b  = blockIdx.x >> 4;
    const int jc = blockIdx.x & 15;
    const int tid = threadIdx.x;

    const size_t xrow = ((size_t)b * Tt + t) * Hh;
    for (int i = tid; i < 512; i += 256) xh[i] = ldin<F32>(xsrc, xrow + i);
    if (t == 0) {
        for (int i = tid; i < 512; i += 256) xh[512 + i] = ldin<F32>(h0, (size_t)b * Hh + i);
    } else {
        for (int i = tid; i < 512; i += 256) xh[512 + i] = h_ws[b * Hh + i];
    }
    __syncthreads();

    const int jl = tid & 31;
    const int kq = tid >> 5;            // 0..7 : kq<4 -> x@Wi, kq>=4 -> h@Wh
    const int j  = jc * 32 + jl;
    const void* Wbase = (kq < 4) ? Wi : Wh;
    const int k0 = (kq & 3) * 128;
    const int xoff = (kq < 4) ? 0 : 512;

    float a0 = 0.f, a1 = 0.f, a2 = 0.f, a3 = 0.f;
    size_t widx = wOff + (size_t)k0 * G4H + j;
    #pragma unroll 4
    for (int k = 0; k < 128; ++k) {
        float xv = xh[xoff + k0 + k];
        a0 += xv * ldin<F32>(Wbase, widx + 0 * Hh);
        a1 += xv * ldin<F32>(Wbase, widx + 1 * Hh);
        a2 += xv * ldin<F32>(Wbase, widx + 2 * Hh);
        a3 += xv * ldin<F32>(Wbase, widx + 3 * Hh);
        widx += G4H;
    }
    red[0][jl][kq] = a0; red[1][jl][kq] = a1;
    red[2][jl][kq] = a2; red[3][jl][kq] = a3;
    __syncthreads();

    if (tid < 128) {
        int g = tid >> 5, jj = tid & 31;
        float s = 0.f;
        #pragma unroll
        for (int q = 0; q < 8; ++q) s += red[g][jj][q];
        ga[g][jj] = s;
    }
    __syncthreads();

    if (tid < 32) {
        int jj = tid;
        int n = jc * 32 + jj;
        float gi = ga[0][jj] + ldin<F32>(bi, bOff + 0 * Hh + n) + ldin<F32>(bh, bOff + 0 * Hh + n);
        float gf = ga[1][jj] + ldin<F32>(bi, bOff + 1 * Hh + n) + ldin<F32>(bh, bOff + 1 * Hh + n);
        float gg = ga[2][jj] + ldin<F32>(bi, bOff + 2 * Hh + n) + ldin<F32>(bh, bOff + 2 * Hh + n);
        float go = ga[3][jj] + ldin<F32>(bi, bOff + 3 * Hh + n) + ldin<F32>(bh, bOff + 3 * Hh + n);
        float ig = 1.f / (1.f + __expf(-gi));
        float fg = 1.f / (1.f + __expf(-gf));
        float g2 = tanhf(gg);
        float og = 1.f / (1.f + __expf(-go));
        float cp = (t == 0) ? ldin<F32>(c0, (size_t)b * Hh + n) : c_ws[b * Hh + n];
        float cy = fg * cp + ig * g2;
        float hy = og * tanhf(cy);
        c_ws[b * Hh + n]  = cy;
        hy_ws[b * Hh + n] = hy;
        if (writeC1) stout<F32>(out, offC1 + (size_t)b * Hh + n, cy);
    }
}

__global__ __launch_bounds__(256) void k_gates(
    const int* flag, const void* xsrc, const void* h0, const void* c0,
    const void* Wi, const void* bi, const void* Wh, const void* bh,
    unsigned long long wOff, unsigned long long bOff,
    const float* h_ws, float* c_ws, float* hy_ws,
    void* out, unsigned long long offC1, int t, int writeC1)
{
    if (*flag) gates_body<true >(xsrc, h0, c0, Wi, bi, Wh, bh, wOff, bOff, h_ws, c_ws, hy_ws, out, offC1, t, writeC1);
    else       gates_body<false>(xsrc, h0, c0, Wi, bi, Wh, bh, wOff, bOff, h_ws, c_ws, hy_ws, out, offC1, t, writeC1);
}

// ---------------------------------------------------------------------------
// K2: target = hy @ Wa_in    grid: 256 = 32 b x 8 nc (64 cols each)
// ---------------------------------------------------------------------------
template<bool F32>
__device__ __forceinline__ void target_body(
    const float* hy_ws, const void* Wa_in, size_t wOff, float* tgt_ws)
{
    __shared__ float hyL[512];
    __shared__ float red[64][4];

    const int b  = blockIdx.x >> 3;
    const int nc = blockIdx.x & 7;
    const int tid = threadIdx.x;

    for (int i = tid; i < 512; i += 256) hyL[i] = hy_ws[b * Hh + i];
    __syncthreads();

    const int nl = tid & 63;
    const int kq = tid >> 6;           // 0..3
    const int n  = nc * 64 + nl;
    const int kb = kq * 128;
    float acc = 0.f;
    #pragma unroll 4
    for (int k = 0; k < 128; ++k)
        acc += hyL[kb + k] * ldin<F32>(Wa_in, wOff + (size_t)(kb + k) * Hh + n);
    red[nl][kq] = acc;
    __syncthreads();

    if (tid < 64) {
        float s = red[tid][0] + red[tid][1] + red[tid][2] + red[tid][3];
        tgt_ws[b * Hh + nc * 64 + tid] = s;
    }
}

__global__ __launch_bounds__(256) void k_target(
    const int* flag, const float* hy_ws, const void* Wa_in,
    unsigned long long wOff, float* tgt_ws)
{
    if (*flag) target_body<true >(hy_ws, Wa_in, wOff, tgt_ws);
    else       target_body<false>(hy_ws, Wa_in, wOff, tgt_ws);
}

// ---------------------------------------------------------------------------
// K3: scores[b][s] = ctx[s][b][:] . target[b][:]
// grid: 4096 blocks x 4 waves, one (b,s) per wave
// ---------------------------------------------------------------------------
template<bool F32>
__device__ __forceinline__ void scores_body(
    const void* ctx, const float* tgt_ws, float* sc_ws)
{
    const int w    = threadIdx.x >> 6;
    const int lane = threadIdx.x & 63;
    const int id = blockIdx.x * 4 + w;     // 0..16383
    const int b = id & 31;
    const int s = id >> 5;

    const size_t base = ((size_t)s * Bb + b) * Hh + lane * 8;
    const float* tp = tgt_ws + (size_t)b * Hh + lane * 8;
    float d = 0.f;
    #pragma unroll
    for (int i = 0; i < 8; ++i) d += ldin<F32>(ctx, base + i) * tp[i];
    #pragma unroll
    for (int o = 32; o > 0; o >>= 1) d += __shfl_xor(d, o);
    if (lane == 0) sc_ws[b * Ss + s] = d;
}

__global__ __launch_bounds__(256) void k_scores(
    const int* flag, const void* ctx, const float* tgt_ws, float* sc_ws)
{
    if (*flag) scores_body<true >(ctx, tgt_ws, sc_ws);
    else       scores_body<false>(ctx, tgt_ws, sc_ws);
}

// ---------------------------------------------------------------------------
// K4: softmax over s (recomputed per block) + wc = sum_s p_s * ctx[s][b][:]
//     + attention-prob output (last layer, hc==0 blocks)
// grid: 128 = 32 b x 4 hc (128 h each), 256 threads
// ---------------------------------------------------------------------------
template<bool F32>
__device__ __forceinline__ void wc_body(
    const void* ctx, const float* sc_ws, float* wc_ws,
    void* out, unsigned long long offAtt, int t, int writeAtt)
{
    __shared__ float scL[512];
    __shared__ float red[256];

    const int b   = blockIdx.x >> 2;
    const int hc  = blockIdx.x & 3;
    const int tid = threadIdx.x;

    scL[tid]       = sc_ws[b * Ss + tid];
    scL[tid + 256] = sc_ws[b * Ss + tid + 256];
    __syncthreads();

    red[tid] = fmaxf(scL[tid], scL[tid + 256]);
    __syncthreads();
    for (int o = 128; o > 0; o >>= 1) {
        if (tid < o) red[tid] = fmaxf(red[tid], red[tid + o]);
        __syncthreads();
    }
    const float M = red[0];
    __syncthreads();

    red[tid] = __expf(scL[tid] - M) + __expf(scL[tid + 256] - M);
    __syncthreads();
    for (int o = 128; o > 0; o >>= 1) {
        if (tid < o) red[tid] += red[tid + o];
        __syncthreads();
    }
    const float inv = 1.f / red[0];
    __syncthreads();                      // red is reused below

    const int h    = hc * 128 + (tid & 127);
    const int half = tid >> 7;
    float acc = 0.f;
    const int s0 = half * 256;
    for (int s = s0; s < s0 + 256; ++s)
        acc += __expf(scL[s] - M) * ldin<F32>(ctx, ((size_t)s * Bb + b) * Hh + h);

    red[tid] = acc;
    __syncthreads();
    if (half == 0)
        wc_ws[b * Hh + h] = (red[tid] + red[tid + 128]) * inv;

    if (writeAtt && hc == 0) {
        float p0 = __expf(scL[tid] - M) * inv;
        float p1 = __expf(scL[tid + 256] - M) * inv;
        stout<F32>(out, offAtt + (size_t)tid         * (Tt * Bb) + (size_t)t * Bb + b, p0);
        stout<F32>(out, offAtt + (size_t)(tid + 256) * (Tt * Bb) + (size_t)t * Bb + b, p1);
    }
}

__global__ __launch_bounds__(256) void k_wc(
    const int* flag, const void* ctx, const float* sc_ws, float* wc_ws,
    void* out, unsigned long long offAtt, int t, int writeAtt)
{
    if (*flag) wc_body<true >(ctx, sc_ws, wc_ws, out, offAtt, t, writeAtt);
    else       wc_body<false>(ctx, sc_ws, wc_ws, out, offAtt, t, writeAtt);
}

// ---------------------------------------------------------------------------
// K5: h_tilde = tanh([wc, hy] @ Wa_out); write h carry, x out, h1 at t==T-1
// grid: 512 = 32 b x 16 nc (32 cols each), 256 threads
// ---------------------------------------------------------------------------
template<bool F32>
__device__ __forceinline__ void out_body(
    const float* hy_ws, const float* wc_ws, const void* Wa_out, size_t wOff,
    float* h_ws, void* out, unsigned long long offH1, int t, int writeH1)
{
    __shared__ float vL[1024];
    __shared__ float red[32][8];

    const int b  = blockIdx.x >> 4;
    const int nc = blockIdx.x & 15;
    const int tid = threadIdx.x;

    for (int h = tid; h < 512; h += 256) {
        vL[h]       = wc_ws[b * Hh + h];
        vL[512 + h] = hy_ws[b * Hh + h];
    }
    __syncthreads();

    const int nl = tid & 31;
    const int kq = tid >> 5;             // 0..7 over 1024 rows
    const int n  = nc * 32 + nl;
    const int kb = kq * 128;
    float acc = 0.f;
    #pragma unroll 4
    for (int k = 0; k < 128; ++k)
        acc += vL[kb + k] * ldin<F32>(Wa_out, wOff + (size_t)(kb + k) * Hh + n);
    red[nl][kq] = acc;
    __syncthreads();

    if (tid < 32) {
        float s = 0.f;
        #pragma unroll
        for (int q = 0; q < 8; ++q) s += red[tid][q];
        float th = tanhf(s);
        int n2 = nc * 32 + tid;
        h_ws[b * Hh + n2] = th;
        stout<F32>(out, ((size_t)b * Tt + t) * Hh + n2, th);
        if (writeH1) stout<F32>(out, offH1 + (size_t)b * Hh + n2, th);
    }
}

__global__ __launch_bounds__(256) void k_out(
    const int* flag, const float* hy_ws, const float* wc_ws, const void* Wa_out,
    unsigned long long wOff, float* h_ws, void* out,
    unsigned long long offH1, int t, int writeH1)
{
    if (*flag) out_body<true >(hy_ws, wc_ws, Wa_out, wOff, h_ws, out, offH1, t, writeH1);
    else       out_body<false>(hy_ws, wc_ws, Wa_out, wOff, h_ws, out, offH1, t, writeH1);
}

// ---------------------------------------------------------------------------
extern "C" void kernel_launch(void* const* d_in, const int* in_sizes, int n_in,
                              void* d_out, int out_size, void* d_ws, size_t ws_size,
                              hipStream_t stream)
{
    const void* input  = d_in[0];
    const void* h0     = d_in[1];
    const void* c0     = d_in[2];
    const void* ctx    = d_in[3];
    const void* Wi     = d_in[4];
    const void* bi     = d_in[5];
    const void* Wh     = d_in[6];
    const void* bh     = d_in[7];
    const void* Wa_in  = d_in[8];
    const void* Wa_out = d_in[9];

    const size_t XN = (size_t)Bb * Tt * Hh;   // 4,194,304
    const size_t HN = (size_t)Bb * Hh;        // 16,384
    const unsigned long long offH1base = XN;
    const unsigned long long offC1base = XN + 2 * HN;
    const unsigned long long offAtt    = XN + 4 * HN;

    int*   flag = (int*)d_ws;
    float* f    = (float*)((char*)d_ws + 16);
    float* h_ws   = f; f += HN;
    float* c_ws   = f; f += HN;
    float* hy_ws  = f; f += HN;
    float* tgt_ws = f; f += HN;
    float* sc_ws  = f; f += (size_t)Bb * Ss;
    float* wc_ws  = f; f += HN;

    k_detect<<<dim3(1), dim3(256), 0, stream>>>(ctx, flag);

    for (int l = 0; l < 2; ++l) {
        const void* xsrc = (l == 0) ? input : (const void*)d_out;
        const unsigned long long wOffG  = (unsigned long long)l * Hh * G4H;
        const unsigned long long bOffG  = (unsigned long long)l * G4H;
        const unsigned long long wOffAi = (unsigned long long)l * Hh * Hh;
        const unsigned long long wOffAo = (unsigned long long)l * 2 * Hh * Hh;
        const unsigned long long offH1  = offH1base + (unsigned long long)l * HN;
        const unsigned long long offC1  = offC1base + (unsigned long long)l * HN;

        for (int t = 0; t < Tt; ++t) {
            const int last = (t == Tt - 1) ? 1 : 0;
            k_gates<<<dim3(512), dim3(256), 0, stream>>>(
                flag, xsrc, h0, c0, Wi, bi, Wh, bh, wOffG, bOffG,
                h_ws, c_ws, hy_ws, d_out, offC1, t, last);
            k_target<<<dim3(256), dim3(256), 0, stream>>>(
                flag, hy_ws, Wa_in, wOffAi, tgt_ws);
            k_scores<<<dim3(4096), dim3(256), 0, stream>>>(
                flag, ctx, tgt_ws, sc_ws);
            k_wc<<<dim3(128), dim3(256), 0, stream>>>(
                flag, ctx, sc_ws, wc_ws, d_out, offAtt, t, l);
            k_out<<<dim3(512), dim3(256), 0, stream>>>(
                flag, hy_ws, wc_ws, Wa_out, wOffAo, h_ws, d_out, offH1, t, last);
        }
    }
}